// Round 6
// baseline (486.082 us; speedup 1.0000x reference)
//
#include <hip/hip_runtime.h>

#define Bdim 8
#define Tdim 2048
#define Cdim 1024
#define NCH 128      // chunks over T
#define CLEN 16      // t-steps per chunk (NCH*CLEN == Tdim)
#define CG 32        // channels per wkv block
#define BC (Bdim*Cdim)

typedef float floatx4 __attribute__((ext_vector_type(4)));
typedef _Float16 half8 __attribute__((ext_vector_type(8)));
typedef _Float16 half4v __attribute__((ext_vector_type(4)));

__device__ __forceinline__ void load16(const void* g, void* l) {
    __builtin_amdgcn_global_load_lds(
        (const __attribute__((address_space(1))) void*)g,
        (__attribute__((address_space(3))) void*)l, 16, 0, 0);
}

// ---------------- Kernel 1: fused embedding gather + time-mix, fp32 -> f16 x3 ----------------
__global__ __launch_bounds__(256) void embed_mix3(const int* __restrict__ tokens,
                                                  const float* __restrict__ xx_init,
                                                  const float* __restrict__ emb,
                                                  const float* __restrict__ tmk,
                                                  const float* __restrict__ tmv,
                                                  const float* __restrict__ tmr,
                                                  _Float16* __restrict__ xk,
                                                  _Float16* __restrict__ xv,
                                                  _Float16* __restrict__ xr) {
    int row = blockIdx.x;              // b*T + t
    int b = row >> 11;
    int t = row & (Tdim - 1);
    const float* cur = emb + (size_t)tokens[row] * Cdim;
    const float* prv = (t == 0) ? (xx_init + (size_t)b * Cdim)
                                : (emb + (size_t)tokens[row - 1] * Cdim);
    int c = threadIdx.x * 4;
    float4 cf4 = *reinterpret_cast<const float4*>(cur + c);
    float4 pf4 = *reinterpret_cast<const float4*>(prv + c);
    float4 mk = *reinterpret_cast<const float4*>(tmk + c);
    float4 mv = *reinterpret_cast<const float4*>(tmv + c);
    float4 mr = *reinterpret_cast<const float4*>(tmr + c);
    float cf[4] = {cf4.x, cf4.y, cf4.z, cf4.w};
    float pf[4] = {pf4.x, pf4.y, pf4.z, pf4.w};
    float mkf[4] = {mk.x, mk.y, mk.z, mk.w};
    float mvf[4] = {mv.x, mv.y, mv.z, mv.w};
    float mrf[4] = {mr.x, mr.y, mr.z, mr.w};
    half4v hk, hv, hr;
    #pragma unroll
    for (int j = 0; j < 4; j++) {
        hk[j] = (_Float16)(mkf[j] * cf[j] + (1.0f - mkf[j]) * pf[j]);
        hv[j] = (_Float16)(mvf[j] * cf[j] + (1.0f - mvf[j]) * pf[j]);
        hr[j] = (_Float16)(mrf[j] * cf[j] + (1.0f - mrf[j]) * pf[j]);
    }
    size_t o = (size_t)row * Cdim + c;
    *reinterpret_cast<half4v*>(xk + o) = hk;
    *reinterpret_cast<half4v*>(xv + o) = hv;
    *reinterpret_cast<half4v*>(xr + o) = hr;
}

// ---------------- Kernel 1c: W fp32 -> f16 ----------------
__global__ __launch_bounds__(256) void wconv(const float* __restrict__ Wk,
                                             const float* __restrict__ Wv,
                                             const float* __restrict__ Wr,
                                             _Float16* __restrict__ Wh) {
    const float* W = blockIdx.y == 0 ? Wk : (blockIdx.y == 1 ? Wv : Wr);
    _Float16* dst = Wh + (size_t)blockIdx.y * Cdim * Cdim;
    int i = (blockIdx.x * 256 + threadIdx.x) * 4;
    float4 f = *reinterpret_cast<const float4*>(W + i);
    half4v h;
    h[0] = (_Float16)f.x; h[1] = (_Float16)f.y; h[2] = (_Float16)f.z; h[3] = (_Float16)f.w;
    *reinterpret_cast<half4v*>(dst + i) = h;
}

// ---------------- Kernel 2: f16 GEMM (NT) + epilogue transpose to [b][c/8][t][8] ----------
// WHICH: 0=k, 1=v, 2=r (sigmoid). One dispatch each -> visible in rocprof top-5.
template<int WHICH>
__global__ __launch_bounds__(256) void gemm_one(const _Float16* __restrict__ X,
                                                const _Float16* __restrict__ Whh,
                                                _Float16* __restrict__ outT) {
    const int lin = blockIdx.x;        // 0..1023
    const int xcd = lin & 7;
    const int loc = lin >> 3;          // 0..127
    const int mt = xcd * 16 + (loc >> 3);
    const int nt = loc & 7;
    const int m0 = mt * 128;
    const int n0 = nt * 128;

    __shared__ _Float16 S[128 * 128];  // K-loop: As | Bs ; epilogue: C-tile
    _Float16* As = S;
    _Float16* Bs = S + 128 * 64;

    const int tid = threadIdx.x;
    const int lane = tid & 63;
    const int wave = tid >> 6;
    const int wm = (wave >> 1) * 64;
    const int wn = (wave & 1) * 64;
    const int lr = lane & 15;
    const int lk = lane >> 4;

    const _Float16* Asrc = X + (size_t)m0 * Cdim;
    const _Float16* Bsrc = Whh + (size_t)n0 * Cdim;

    floatx4 acc[4][4] = {};

    for (int k0 = 0; k0 < Cdim; k0 += 64) {
        #pragma unroll
        for (int i = 0; i < 4; i++) {
            int e = i * 256 + tid;
            int r = e >> 3;
            int cbp = e & 7;
            int cbl = cbp ^ (r & 7);
            load16(Asrc + (size_t)r * Cdim + k0 + cbl * 8, (char*)As + e * 16);
            load16(Bsrc + (size_t)r * Cdim + k0 + cbl * 8, (char*)Bs + e * 16);
        }
        __syncthreads();
        #pragma unroll
        for (int kk = 0; kk < 64; kk += 32) {
            const int kb_ = kk >> 3;
            half8 af[4], bf[4];
            #pragma unroll
            for (int mi = 0; mi < 4; mi++) {
                int r = wm + mi * 16 + lr;
                int cb = (kb_ + lk) ^ (r & 7);
                af[mi] = *reinterpret_cast<const half8*>(As + r * 64 + cb * 8);
            }
            #pragma unroll
            for (int ni = 0; ni < 4; ni++) {
                int r = wn + ni * 16 + lr;
                int cb = (kb_ + lk) ^ (r & 7);
                bf[ni] = *reinterpret_cast<const half8*>(Bs + r * 64 + cb * 8);
            }
            #pragma unroll
            for (int mi = 0; mi < 4; mi++)
                #pragma unroll
                for (int ni = 0; ni < 4; ni++)
                    acc[mi][ni] = __builtin_amdgcn_mfma_f32_16x16x32_f16(af[mi], bf[ni], acc[mi][ni], 0, 0, 0);
        }
        __syncthreads();    // final iter: LDS free for epilogue reuse after this
    }

    // ---- epilogue: C fragments -> LDS (XOR-swizzled col-blocks) ----
    #pragma unroll
    for (int mi = 0; mi < 4; mi++) {
        #pragma unroll
        for (int ni = 0; ni < 4; ni++) {
            #pragma unroll
            for (int reg = 0; reg < 4; reg++) {
                int mm = wm + mi * 16 + (lane >> 4) * 4 + reg;   // t within tile
                int nn = wn + ni * 16 + (lane & 15);             // c within tile
                float v = acc[mi][ni][reg];
                if (WHICH == 2) v = 1.0f / (1.0f + __expf(-v));
                int cb = nn >> 3, e = nn & 7;
                S[mm * 128 + ((cb ^ (mm & 15)) << 3) + e] = (_Float16)v;
            }
        }
    }
    __syncthreads();
    // ---- LDS -> global in [b][cg8][t][8] layout; lanes sweep t for coalescing ----
    const int bb = m0 >> 11;
    const int t0 = m0 & (Tdim - 1);
    const int g0 = n0 >> 3;
    #pragma unroll
    for (int i = 0; i < 8; i++) {
        int idx = i * 256 + tid;       // 0..2047
        int mm = idx & 127;
        int cg8 = idx >> 7;            // 0..15
        half8 val = *reinterpret_cast<const half8*>(&S[mm * 128 + ((cg8 ^ (mm & 15)) << 3)]);
        *reinterpret_cast<half8*>(outT + (((size_t)bb * 128 + g0 + cg8) * Tdim + t0 + mm) * 8) = val;
    }
}

// ---------------- Kernel 3: fully fused WKV scan on transposed layout ----------------
// block = (b, 32 channels); 512 threads = 128 chunks x 4 c8-groups; 8 ch/thread.
// Reads are 16B-contiguous streams (256B per thread per chunk phase).
__global__ __launch_bounds__(512) void wkv_fused(const _Float16* __restrict__ kT,
                                                 const _Float16* __restrict__ vT,
                                                 const _Float16* __restrict__ rT,
                                                 const float* __restrict__ tdecay,
                                                 const float* __restrict__ tfirst,
                                                 const float* __restrict__ aa_init,
                                                 const float* __restrict__ bb_init,
                                                 const float* __restrict__ pp_init,
                                                 float* __restrict__ z) {
    __shared__ float sa[NCH * CG];
    __shared__ float sbv[NCH * CG];
    __shared__ float sp[NCH * CG];
    __shared__ float ssum[NCH * CG];
    __shared__ float s2[8 * CG];
    __shared__ float syl[CG];

    const int b = blockIdx.x >> 5;
    const int cgrp = blockIdx.x & 31;          // 32-ch group within C
    const int tid = threadIdx.x;
    const int grp = tid & 3;                   // c8 group within block
    const int j = tid >> 2;                    // chunk 0..127
    const int cg8 = cgrp * 4 + grp;            // global c8 group
    const int c0 = cg8 * 8;

    float4 td0 = *reinterpret_cast<const float4*>(tdecay + c0);
    float4 td1 = *reinterpret_cast<const float4*>(tdecay + c0 + 4);
    float4 u0 = *reinterpret_cast<const float4*>(tfirst + c0);
    float4 u1 = *reinterpret_cast<const float4*>(tfirst + c0 + 4);
    float w[8] = {-__expf(td0.x), -__expf(td0.y), -__expf(td0.z), -__expf(td0.w),
                  -__expf(td1.x), -__expf(td1.y), -__expf(td1.z), -__expf(td1.w)};
    float u[8] = {u0.x, u0.y, u0.z, u0.w, u1.x, u1.y, u1.z, u1.w};

    const size_t base = (((size_t)b * 128 + cg8) * Tdim + j * CLEN) * 8;
    const _Float16* kp = kT + base;
    const _Float16* vp = vT + base;
    const _Float16* rp = rT + base;

    // ---- phase 1: chunk-local scan (zero start) ----
    float aa[8], bb[8], pp[8];
    #pragma unroll
    for (int i = 0; i < 8; i++) { aa[i] = 0.0f; bb[i] = 0.0f; pp[i] = -1e30f; }
    #pragma unroll 4
    for (int t = 0; t < CLEN; t++) {
        half8 k8 = *reinterpret_cast<const half8*>(kp + t * 8);
        half8 v8 = *reinterpret_cast<const half8*>(vp + t * 8);
        #pragma unroll
        for (int i = 0; i < 8; i++) {
            float kt = (float)k8[i];
            float vt = (float)v8[i];
            float ww2 = pp[i] + w[i];
            float p2 = fmaxf(ww2, kt);
            float e1 = __expf(ww2 - p2);
            float e2 = __expf(kt - p2);
            aa[i] = e1 * aa[i] + e2 * vt;
            bb[i] = e1 * bb[i] + e2;
            pp[i] = p2;
        }
    }
    {
        int o = j * CG + grp * 8;
        #pragma unroll
        for (int i = 0; i < 8; i++) { sa[o + i] = aa[i]; sbv[o + i] = bb[i]; sp[o + i] = pp[i]; }
    }
    __syncthreads();

    // ---- phase 2: sequential combine over chunks in LDS, in-place -> incoming states ----
    if (tid < CG) {
        int ch = tid;
        float w1 = -__expf(tdecay[cgrp * CG + ch]);
        float wL = w1 * (float)CLEN;
        int gidx = b * Cdim + cgrp * CG + ch;
        float a = aa_init[gidx], bv = bb_init[gidx], p = pp_init[gidx];
        for (int jj = 0; jj < NCH; jj++) {
            int o = jj * CG + ch;
            float ta = sa[o], tb = sbv[o], tp = sp[o];
            sa[o] = a; sbv[o] = bv; sp[o] = p;
            float px = p + wL;
            float q = fmaxf(px, tp);
            float e1 = __expf(px - q);
            float e2 = __expf(tp - q);
            a = e1 * a + e2 * ta;
            bv = e1 * bv + e2 * tb;
            p = q;
        }
    }
    __syncthreads();

    // ---- phase 3: replay with incoming state ----
    float sum[8], ylv[8];
    {
        int o = j * CG + grp * 8;
        #pragma unroll
        for (int i = 0; i < 8; i++) {
            aa[i] = sa[o + i]; bb[i] = sbv[o + i]; pp[i] = sp[o + i];
            sum[i] = 0.0f; ylv[i] = 0.0f;
        }
    }
    #pragma unroll 4
    for (int t = 0; t < CLEN; t++) {
        half8 k8 = *reinterpret_cast<const half8*>(kp + t * 8);
        half8 v8 = *reinterpret_cast<const half8*>(vp + t * 8);
        half8 r8 = *reinterpret_cast<const half8*>(rp + t * 8);
        #pragma unroll
        for (int i = 0; i < 8; i++) {
            float kt = (float)k8[i];
            float vt = (float)v8[i];
            float rt = (float)r8[i];
            float ww = u[i] + kt;
            float p = fmaxf(pp[i], ww);
            float e1 = __expf(pp[i] - p);
            float e2 = __expf(ww - p);
            float wkv = (e1 * aa[i] + e2 * vt) / (e1 * bb[i] + e2);
            float y = rt * wkv;
            sum[i] += y;
            ylv[i] = y;
            float ww2 = pp[i] + w[i];
            float p2 = fmaxf(ww2, kt);
            float e1b = __expf(ww2 - p2);
            float e2b = __expf(kt - p2);
            aa[i] = e1b * aa[i] + e2b * vt;
            bb[i] = e1b * bb[i] + e2b;
            pp[i] = p2;
        }
    }
    {
        int o = j * CG + grp * 8;
        #pragma unroll
        for (int i = 0; i < 8; i++) ssum[o + i] = sum[i];
        if (j == NCH - 1) {
            #pragma unroll
            for (int i = 0; i < 8; i++) syl[grp * 8 + i] = ylv[i];
        }
    }
    __syncthreads();

    // ---- reduce: sum over 128 chunks per channel ----
    if (tid < 256) {
        int ch = tid & 31, s = tid >> 5;    // 8 slices x 16 chunks
        float acc = 0.0f;
        #pragma unroll
        for (int jj = 0; jj < 16; jj++) acc += ssum[(s * 16 + jj) * CG + ch];
        s2[s * CG + ch] = acc;
    }
    __syncthreads();
    if (tid < CG) {
        float acc = 0.0f;
        #pragma unroll
        for (int s = 0; s < 8; s++) acc += s2[s * CG + tid];
        z[(size_t)b * Cdim + cgrp * CG + tid] = 0.5f * (syl[tid] + acc * (1.0f / (float)Tdim));
    }
}

// ---------------- Kernel 7: hx[b,d] = sum_c z[b,c]*Wo[d,c]; write twice ----------------
__global__ __launch_bounds__(256) void final_out(const float* __restrict__ z,
                                                 const float* __restrict__ Wo,
                                                 float* __restrict__ out) {
    int gw = (blockIdx.x * 256 + threadIdx.x) >> 6;   // global wave id, 0..BC-1
    int lane = threadIdx.x & 63;
    int b = gw >> 10;
    int d = gw & (Cdim - 1);
    const float4* zr = reinterpret_cast<const float4*>(z + (size_t)b * Cdim);
    const float4* wr = reinterpret_cast<const float4*>(Wo + (size_t)d * Cdim);
    float acc = 0.0f;
    #pragma unroll
    for (int s = 0; s < 4; s++) {
        float4 a = zr[lane + 64 * s];
        float4 w4 = wr[lane + 64 * s];
        acc += a.x * w4.x + a.y * w4.y + a.z * w4.z + a.w * w4.w;
    }
    #pragma unroll
    for (int off = 32; off > 0; off >>= 1) acc += __shfl_down(acc, off);
    if (lane == 0) {
        out[(size_t)b * Cdim + d] = acc;
        out[(size_t)BC + (size_t)b * Cdim + d] = acc;
    }
}

extern "C" void kernel_launch(void* const* d_in, const int* in_sizes, int n_in,
                              void* d_out, int out_size, void* d_ws, size_t ws_size,
                              hipStream_t stream) {
    const int*   tokens  = (const int*)d_in[0];
    const float* xx_init = (const float*)d_in[1];
    const float* aa_init = (const float*)d_in[2];
    const float* bb_init = (const float*)d_in[3];
    const float* pp_init = (const float*)d_in[4];
    const float* emb     = (const float*)d_in[5];
    const float* tmk     = (const float*)d_in[6];
    const float* tmv     = (const float*)d_in[7];
    const float* tmr     = (const float*)d_in[8];
    const float* tdecay  = (const float*)d_in[9];
    const float* tfirst  = (const float*)d_in[10];
    const float* Wk      = (const float*)d_in[11];
    const float* Wv      = (const float*)d_in[12];
    const float* Wr      = (const float*)d_in[13];
    const float* Wo      = (const float*)d_in[14];
    float* out = (float*)d_out;

    char* ws = (char*)d_ws;
    size_t off = 0;
    auto alloc = [&](size_t bytes) -> void* {
        void* p = ws + off;
        off += (bytes + 255) & ~(size_t)255;
        return p;
    };
    _Float16* xkb = (_Float16*)alloc((size_t)Bdim * Tdim * Cdim * 2);
    _Float16* xvb = (_Float16*)alloc((size_t)Bdim * Tdim * Cdim * 2);
    _Float16* xrb = (_Float16*)alloc((size_t)Bdim * Tdim * Cdim * 2);
    _Float16* kb = (_Float16*)alloc((size_t)Bdim * Tdim * Cdim * 2);
    _Float16* vb = (_Float16*)alloc((size_t)Bdim * Tdim * Cdim * 2);
    _Float16* rb = (_Float16*)alloc((size_t)Bdim * Tdim * Cdim * 2);
    _Float16* Wh = (_Float16*)alloc((size_t)3 * Cdim * Cdim * 2);
    float* zbuf = (float*)alloc((size_t)BC * 4);

    embed_mix3<<<Bdim * Tdim, 256, 0, stream>>>(tokens, xx_init, emb, tmk, tmv, tmr,
                                                xkb, xvb, xrb);
    wconv<<<dim3(1024, 3), 256, 0, stream>>>(Wk, Wv, Wr, Wh);
    gemm_one<0><<<1024, 256, 0, stream>>>(xkb, Wh, kb);
    gemm_one<1><<<1024, 256, 0, stream>>>(xvb, Wh + (size_t)Cdim * Cdim, vb);
    gemm_one<2><<<1024, 256, 0, stream>>>(xrb, Wh + (size_t)2 * Cdim * Cdim, rb);
    wkv_fused<<<Bdim * 32, 512, 0, stream>>>(kb, vb, rb, tdecay, tfirst,
                                             aa_init, bb_init, pp_init, zbuf);
    final_out<<<(BC / 4), 256, 0, stream>>>(zbuf, Wo, out);
}

// Round 7
// 433.776 us; speedup vs baseline: 1.1206x; 1.1206x over previous
//
#include <hip/hip_runtime.h>

#define Bdim 8
#define Tdim 2048
#define Cdim 1024
#define NCH 128      // chunks over T
#define CLEN 16      // t-steps per chunk (NCH*CLEN == Tdim)
#define CG 16        // channels per wkv block
#define BC (Bdim*Cdim)

typedef float floatx4 __attribute__((ext_vector_type(4)));
typedef _Float16 half8 __attribute__((ext_vector_type(8)));
typedef _Float16 half4v __attribute__((ext_vector_type(4)));

__device__ __forceinline__ void load16(const void* g, void* l) {
    __builtin_amdgcn_global_load_lds(
        (const __attribute__((address_space(1))) void*)g,
        (__attribute__((address_space(3))) void*)l, 16, 0, 0);
}

// ---------------- Kernel 1: fused embedding gather + time-mix, fp32 -> f16 x3 ----------------
__global__ __launch_bounds__(256) void embed_mix3(const int* __restrict__ tokens,
                                                  const float* __restrict__ xx_init,
                                                  const float* __restrict__ emb,
                                                  const float* __restrict__ tmk,
                                                  const float* __restrict__ tmv,
                                                  const float* __restrict__ tmr,
                                                  _Float16* __restrict__ xk,
                                                  _Float16* __restrict__ xv,
                                                  _Float16* __restrict__ xr) {
    int row = blockIdx.x;              // b*T + t
    int b = row >> 11;
    int t = row & (Tdim - 1);
    const float* cur = emb + (size_t)tokens[row] * Cdim;
    const float* prv = (t == 0) ? (xx_init + (size_t)b * Cdim)
                                : (emb + (size_t)tokens[row - 1] * Cdim);
    int c = threadIdx.x * 4;
    float4 cf4 = *reinterpret_cast<const float4*>(cur + c);
    float4 pf4 = *reinterpret_cast<const float4*>(prv + c);
    float4 mk = *reinterpret_cast<const float4*>(tmk + c);
    float4 mv = *reinterpret_cast<const float4*>(tmv + c);
    float4 mr = *reinterpret_cast<const float4*>(tmr + c);
    float cf[4] = {cf4.x, cf4.y, cf4.z, cf4.w};
    float pf[4] = {pf4.x, pf4.y, pf4.z, pf4.w};
    float mkf[4] = {mk.x, mk.y, mk.z, mk.w};
    float mvf[4] = {mv.x, mv.y, mv.z, mv.w};
    float mrf[4] = {mr.x, mr.y, mr.z, mr.w};
    half4v hk, hv, hr;
    #pragma unroll
    for (int j = 0; j < 4; j++) {
        hk[j] = (_Float16)(mkf[j] * cf[j] + (1.0f - mkf[j]) * pf[j]);
        hv[j] = (_Float16)(mvf[j] * cf[j] + (1.0f - mvf[j]) * pf[j]);
        hr[j] = (_Float16)(mrf[j] * cf[j] + (1.0f - mrf[j]) * pf[j]);
    }
    size_t o = (size_t)row * Cdim + c;
    *reinterpret_cast<half4v*>(xk + o) = hk;
    *reinterpret_cast<half4v*>(xv + o) = hv;
    *reinterpret_cast<half4v*>(xr + o) = hr;
}

// ---------------- Kernel 1c: W fp32 -> f16 ----------------
__global__ __launch_bounds__(256) void wconv(const float* __restrict__ Wk,
                                             const float* __restrict__ Wv,
                                             const float* __restrict__ Wr,
                                             _Float16* __restrict__ Wh) {
    const float* W = blockIdx.y == 0 ? Wk : (blockIdx.y == 1 ? Wv : Wr);
    _Float16* dst = Wh + (size_t)blockIdx.y * Cdim * Cdim;
    int i = (blockIdx.x * 256 + threadIdx.x) * 4;
    float4 f = *reinterpret_cast<const float4*>(W + i);
    half4v h;
    h[0] = (_Float16)f.x; h[1] = (_Float16)f.y; h[2] = (_Float16)f.z; h[3] = (_Float16)f.w;
    *reinterpret_cast<half4v*>(dst + i) = h;
}

// ---------------- Kernel 2: f16 GEMM (NT) + epilogue transpose to [b][c/8][t][8] ----------
template<int WHICH>
__global__ __launch_bounds__(256) void gemm_one(const _Float16* __restrict__ X,
                                                const _Float16* __restrict__ Whh,
                                                _Float16* __restrict__ outT) {
    const int lin = blockIdx.x;        // 0..1023
    const int xcd = lin & 7;
    const int loc = lin >> 3;          // 0..127
    const int mt = xcd * 16 + (loc >> 3);
    const int nt = loc & 7;
    const int m0 = mt * 128;
    const int n0 = nt * 128;

    __shared__ _Float16 S[128 * 128];  // K-loop: As | Bs ; epilogue: C-tile
    _Float16* As = S;
    _Float16* Bs = S + 128 * 64;

    const int tid = threadIdx.x;
    const int lane = tid & 63;
    const int wave = tid >> 6;
    const int wm = (wave >> 1) * 64;
    const int wn = (wave & 1) * 64;
    const int lr = lane & 15;
    const int lk = lane >> 4;

    const _Float16* Asrc = X + (size_t)m0 * Cdim;
    const _Float16* Bsrc = Whh + (size_t)n0 * Cdim;

    floatx4 acc[4][4] = {};

    for (int k0 = 0; k0 < Cdim; k0 += 64) {
        #pragma unroll
        for (int i = 0; i < 4; i++) {
            int e = i * 256 + tid;
            int r = e >> 3;
            int cbp = e & 7;
            int cbl = cbp ^ (r & 7);
            load16(Asrc + (size_t)r * Cdim + k0 + cbl * 8, (char*)As + e * 16);
            load16(Bsrc + (size_t)r * Cdim + k0 + cbl * 8, (char*)Bs + e * 16);
        }
        __syncthreads();
        #pragma unroll
        for (int kk = 0; kk < 64; kk += 32) {
            const int kb_ = kk >> 3;
            half8 af[4], bf[4];
            #pragma unroll
            for (int mi = 0; mi < 4; mi++) {
                int r = wm + mi * 16 + lr;
                int cb = (kb_ + lk) ^ (r & 7);
                af[mi] = *reinterpret_cast<const half8*>(As + r * 64 + cb * 8);
            }
            #pragma unroll
            for (int ni = 0; ni < 4; ni++) {
                int r = wn + ni * 16 + lr;
                int cb = (kb_ + lk) ^ (r & 7);
                bf[ni] = *reinterpret_cast<const half8*>(Bs + r * 64 + cb * 8);
            }
            #pragma unroll
            for (int mi = 0; mi < 4; mi++)
                #pragma unroll
                for (int ni = 0; ni < 4; ni++)
                    acc[mi][ni] = __builtin_amdgcn_mfma_f32_16x16x32_f16(af[mi], bf[ni], acc[mi][ni], 0, 0, 0);
        }
        __syncthreads();
    }

    // ---- epilogue: C fragments -> LDS (XOR-swizzled col-blocks) ----
    #pragma unroll
    for (int mi = 0; mi < 4; mi++) {
        #pragma unroll
        for (int ni = 0; ni < 4; ni++) {
            #pragma unroll
            for (int reg = 0; reg < 4; reg++) {
                int mm = wm + mi * 16 + (lane >> 4) * 4 + reg;   // t within tile
                int nn = wn + ni * 16 + (lane & 15);             // c within tile
                float v = acc[mi][ni][reg];
                if (WHICH == 2) v = 1.0f / (1.0f + __expf(-v));
                int cb = nn >> 3, e = nn & 7;
                S[mm * 128 + ((cb ^ (mm & 15)) << 3) + e] = (_Float16)v;
            }
        }
    }
    __syncthreads();
    // ---- LDS -> global in [b][cg8][t][8] layout; lanes sweep t for coalescing ----
    const int bb = m0 >> 11;
    const int t0 = m0 & (Tdim - 1);
    const int g0 = n0 >> 3;
    #pragma unroll
    for (int i = 0; i < 8; i++) {
        int idx = i * 256 + tid;       // 0..2047
        int mm = idx & 127;
        int cg8 = idx >> 7;            // 0..15
        half8 val = *reinterpret_cast<const half8*>(&S[mm * 128 + ((cg8 ^ (mm & 15)) << 3)]);
        *reinterpret_cast<half8*>(outT + (((size_t)bb * 128 + g0 + cg8) * Tdim + t0 + mm) * 8) = val;
    }
}

// ---------------- Kernel 3: fused WKV scan v2: 512 blocks x 256 thr, batched loads ----------
// block = (b, 16 channels); threads: g = tid>>7 (c8 group), j = tid&127 (chunk); 8 ch/thread.
__global__ __launch_bounds__(256) void wkv_fused(const _Float16* __restrict__ kT,
                                                 const _Float16* __restrict__ vT,
                                                 const _Float16* __restrict__ rT,
                                                 const float* __restrict__ tdecay,
                                                 const float* __restrict__ tfirst,
                                                 const float* __restrict__ aa_init,
                                                 const float* __restrict__ bb_init,
                                                 const float* __restrict__ pp_init,
                                                 float* __restrict__ z) {
    __shared__ float sa[NCH * CG];
    __shared__ float sbv[NCH * CG];
    __shared__ float sp[NCH * CG];
    __shared__ float ssum[NCH * CG];
    __shared__ float s2[16 * CG];
    __shared__ float syl[CG];

    const int b = blockIdx.x >> 6;
    const int cgrp = blockIdx.x & 63;          // 16-ch group within C
    const int tid = threadIdx.x;
    const int g = tid >> 7;                    // c8 group within block (0..1)
    const int j = tid & 127;                   // chunk 0..127
    const int cg8 = cgrp * 2 + g;              // global c8 group
    const int c0 = cg8 * 8;

    float4 td0 = *reinterpret_cast<const float4*>(tdecay + c0);
    float4 td1 = *reinterpret_cast<const float4*>(tdecay + c0 + 4);
    float4 u0 = *reinterpret_cast<const float4*>(tfirst + c0);
    float4 u1 = *reinterpret_cast<const float4*>(tfirst + c0 + 4);
    float w[8] = {-__expf(td0.x), -__expf(td0.y), -__expf(td0.z), -__expf(td0.w),
                  -__expf(td1.x), -__expf(td1.y), -__expf(td1.z), -__expf(td1.w)};
    float u[8] = {u0.x, u0.y, u0.z, u0.w, u1.x, u1.y, u1.z, u1.w};

    const size_t base = (((size_t)b * 128 + cg8) * Tdim + j * CLEN) * 8;
    const half8* kp8 = reinterpret_cast<const half8*>(kT + base);
    const half8* vp8 = reinterpret_cast<const half8*>(vT + base);
    const half8* rp8 = reinterpret_cast<const half8*>(rT + base);

    // ---- phase 1: chunk-local scan (zero start), batched 8-step loads ----
    float aa[8], bb[8], pp[8];
    #pragma unroll
    for (int i = 0; i < 8; i++) { aa[i] = 0.0f; bb[i] = 0.0f; pp[i] = -1e30f; }
    #pragma unroll
    for (int hb = 0; hb < 2; hb++) {
        half8 kbuf[8], vbuf[8];
        #pragma unroll
        for (int t = 0; t < 8; t++) kbuf[t] = kp8[hb * 8 + t];
        #pragma unroll
        for (int t = 0; t < 8; t++) vbuf[t] = vp8[hb * 8 + t];
        #pragma unroll
        for (int t = 0; t < 8; t++) {
            #pragma unroll
            for (int i = 0; i < 8; i++) {
                float kt = (float)kbuf[t][i];
                float vt = (float)vbuf[t][i];
                float ww2 = pp[i] + w[i];
                float p2 = fmaxf(ww2, kt);
                float e1 = __expf(ww2 - p2);
                float e2 = __expf(kt - p2);
                aa[i] = e1 * aa[i] + e2 * vt;
                bb[i] = e1 * bb[i] + e2;
                pp[i] = p2;
            }
        }
    }
    {
        int o = j * CG + g * 8;
        #pragma unroll
        for (int i = 0; i < 8; i++) { sa[o + i] = aa[i]; sbv[o + i] = bb[i]; sp[o + i] = pp[i]; }
    }
    __syncthreads();

    // ---- phase 2: sequential combine over chunks in LDS, in-place -> incoming states ----
    if (tid < CG) {
        int ch = tid;
        float w1 = -__expf(tdecay[cgrp * CG + ch]);
        float wL = w1 * (float)CLEN;
        int gidx = b * Cdim + cgrp * CG + ch;
        float a = aa_init[gidx], bv = bb_init[gidx], p = pp_init[gidx];
        for (int jj = 0; jj < NCH; jj++) {
            int o = jj * CG + ch;
            float ta = sa[o], tb = sbv[o], tp = sp[o];
            sa[o] = a; sbv[o] = bv; sp[o] = p;
            float px = p + wL;
            float q = fmaxf(px, tp);
            float e1 = __expf(px - q);
            float e2 = __expf(tp - q);
            a = e1 * a + e2 * ta;
            bv = e1 * bv + e2 * tb;
            p = q;
        }
    }
    __syncthreads();

    // ---- phase 3: replay with incoming state, batched loads ----
    float sum[8], ylv[8];
    {
        int o = j * CG + g * 8;
        #pragma unroll
        for (int i = 0; i < 8; i++) {
            aa[i] = sa[o + i]; bb[i] = sbv[o + i]; pp[i] = sp[o + i];
            sum[i] = 0.0f; ylv[i] = 0.0f;
        }
    }
    #pragma unroll
    for (int hb = 0; hb < 2; hb++) {
        half8 kbuf[8], vbuf[8], rbuf[8];
        #pragma unroll
        for (int t = 0; t < 8; t++) kbuf[t] = kp8[hb * 8 + t];
        #pragma unroll
        for (int t = 0; t < 8; t++) vbuf[t] = vp8[hb * 8 + t];
        #pragma unroll
        for (int t = 0; t < 8; t++) rbuf[t] = rp8[hb * 8 + t];
        #pragma unroll
        for (int t = 0; t < 8; t++) {
            #pragma unroll
            for (int i = 0; i < 8; i++) {
                float kt = (float)kbuf[t][i];
                float vt = (float)vbuf[t][i];
                float rt = (float)rbuf[t][i];
                float ww = u[i] + kt;
                float p = fmaxf(pp[i], ww);
                float e1 = __expf(pp[i] - p);
                float e2 = __expf(ww - p);
                float wkv = (e1 * aa[i] + e2 * vt) / (e1 * bb[i] + e2);
                float y = rt * wkv;
                sum[i] += y;
                ylv[i] = y;
                float ww2 = pp[i] + w[i];
                float p2 = fmaxf(ww2, kt);
                float e1b = __expf(ww2 - p2);
                float e2b = __expf(kt - p2);
                aa[i] = e1b * aa[i] + e2b * vt;
                bb[i] = e1b * bb[i] + e2b;
                pp[i] = p2;
            }
        }
    }
    {
        int o = j * CG + g * 8;
        #pragma unroll
        for (int i = 0; i < 8; i++) ssum[o + i] = sum[i];
        if (j == NCH - 1) {
            #pragma unroll
            for (int i = 0; i < 8; i++) syl[g * 8 + i] = ylv[i];
        }
    }
    __syncthreads();

    // ---- reduce: sum over 128 chunks per channel ----
    {
        int ch = tid & 15, s = tid >> 4;    // 16 slices x 8 chunks
        float acc = 0.0f;
        #pragma unroll
        for (int jj = 0; jj < 8; jj++) acc += ssum[(s * 8 + jj) * CG + ch];
        s2[s * CG + ch] = acc;
    }
    __syncthreads();
    if (tid < CG) {
        float acc = 0.0f;
        #pragma unroll
        for (int s = 0; s < 16; s++) acc += s2[s * CG + tid];
        z[(size_t)b * Cdim + cgrp * CG + tid] = 0.5f * (syl[tid] + acc * (1.0f / (float)Tdim));
    }
}

// ---------------- Kernel 7: hx[b,d] = sum_c z[b,c]*Wo[d,c]; write twice ----------------
__global__ __launch_bounds__(256) void final_out(const float* __restrict__ z,
                                                 const float* __restrict__ Wo,
                                                 float* __restrict__ out) {
    int gw = (blockIdx.x * 256 + threadIdx.x) >> 6;   // global wave id, 0..BC-1
    int lane = threadIdx.x & 63;
    int b = gw >> 10;
    int d = gw & (Cdim - 1);
    const float4* zr = reinterpret_cast<const float4*>(z + (size_t)b * Cdim);
    const float4* wr = reinterpret_cast<const float4*>(Wo + (size_t)d * Cdim);
    float acc = 0.0f;
    #pragma unroll
    for (int s = 0; s < 4; s++) {
        float4 a = zr[lane + 64 * s];
        float4 w4 = wr[lane + 64 * s];
        acc += a.x * w4.x + a.y * w4.y + a.z * w4.z + a.w * w4.w;
    }
    #pragma unroll
    for (int off = 32; off > 0; off >>= 1) acc += __shfl_down(acc, off);
    if (lane == 0) {
        out[(size_t)b * Cdim + d] = acc;
        out[(size_t)BC + (size_t)b * Cdim + d] = acc;
    }
}

extern "C" void kernel_launch(void* const* d_in, const int* in_sizes, int n_in,
                              void* d_out, int out_size, void* d_ws, size_t ws_size,
                              hipStream_t stream) {
    const int*   tokens  = (const int*)d_in[0];
    const float* xx_init = (const float*)d_in[1];
    const float* aa_init = (const float*)d_in[2];
    const float* bb_init = (const float*)d_in[3];
    const float* pp_init = (const float*)d_in[4];
    const float* emb     = (const float*)d_in[5];
    const float* tmk     = (const float*)d_in[6];
    const float* tmv     = (const float*)d_in[7];
    const float* tmr     = (const float*)d_in[8];
    const float* tdecay  = (const float*)d_in[9];
    const float* tfirst  = (const float*)d_in[10];
    const float* Wk      = (const float*)d_in[11];
    const float* Wv      = (const float*)d_in[12];
    const float* Wr      = (const float*)d_in[13];
    const float* Wo      = (const float*)d_in[14];
    float* out = (float*)d_out;

    char* ws = (char*)d_ws;
    size_t off = 0;
    auto alloc = [&](size_t bytes) -> void* {
        void* p = ws + off;
        off += (bytes + 255) & ~(size_t)255;
        return p;
    };
    _Float16* xkb = (_Float16*)alloc((size_t)Bdim * Tdim * Cdim * 2);
    _Float16* xvb = (_Float16*)alloc((size_t)Bdim * Tdim * Cdim * 2);
    _Float16* xrb = (_Float16*)alloc((size_t)Bdim * Tdim * Cdim * 2);
    _Float16* kb = (_Float16*)alloc((size_t)Bdim * Tdim * Cdim * 2);
    _Float16* vb = (_Float16*)alloc((size_t)Bdim * Tdim * Cdim * 2);
    _Float16* rb = (_Float16*)alloc((size_t)Bdim * Tdim * Cdim * 2);
    _Float16* Wh = (_Float16*)alloc((size_t)3 * Cdim * Cdim * 2);
    float* zbuf = (float*)alloc((size_t)BC * 4);

    embed_mix3<<<Bdim * Tdim, 256, 0, stream>>>(tokens, xx_init, emb, tmk, tmv, tmr,
                                                xkb, xvb, xrb);
    wconv<<<dim3(1024, 3), 256, 0, stream>>>(Wk, Wv, Wr, Wh);
    gemm_one<0><<<1024, 256, 0, stream>>>(xkb, Wh, kb);
    gemm_one<1><<<1024, 256, 0, stream>>>(xvb, Wh + (size_t)Cdim * Cdim, vb);
    gemm_one<2><<<1024, 256, 0, stream>>>(xrb, Wh + (size_t)2 * Cdim * Cdim, rb);
    wkv_fused<<<Bdim * 64, 256, 0, stream>>>(kb, vb, rb, tdecay, tfirst,
                                             aa_init, bb_init, pp_init, zbuf);
    final_out<<<(BC / 4), 256, 0, stream>>>(zbuf, Wo, out);
}